// Round 7
// baseline (240.162 us; speedup 1.0000x reference)
//
#include <hip/hip_runtime.h>
#include <hip/hip_bf16.h>
#include <cstdint>
#include <cstddef>

// Problem constants (match reference)
#define Bc 2
#define Mc 2048
#define Rc 256
#define Hc 16
#define DHc 64
#define Dc (Hc * DHc)
#define NKT (Mc / 64)      // 32 key tiles of 64

typedef __attribute__((ext_vector_type(8))) short short8;     // 8 bf16 (4 VGPRs)
typedef __attribute__((ext_vector_type(4))) float float4v;    // MFMA C/D frag
typedef __attribute__((ext_vector_type(4))) unsigned short ushort4v;
typedef __attribute__((ext_vector_type(8))) unsigned short ushort8v;
typedef __attribute__((ext_vector_type(4))) unsigned int uint4v;

// exp path: native exp2 (v_exp_f32); 0.125*log2(e) folded into Q at proj
#if __has_builtin(__builtin_amdgcn_exp2f)
#define EXPFN(x) __builtin_amdgcn_exp2f(x)
#define QSCALE 0.18033688f       // 0.125 * log2(e)
#define MADD_KEEP (-28.8539008f) // -20 * log2(e)
#else
#define EXPFN(x) __expf(x)
#define QSCALE 0.125f
#define MADD_KEEP (-20.0f)
#endif

// round-to-nearest-even f32 -> bf16
__device__ inline unsigned short f2bf(float f) {
    union { float f; uint32_t u; } v;
    v.f = f;
    uint32_t r = v.u + 0x7fffu + ((v.u >> 16) & 1u);
    return (unsigned short)(r >> 16);
}

// XOR-swizzled byte offset for [row][8 x 16B-chunk] LDS tiles (row = 128 B).
__device__ inline int swz(int row, int chunk) {
    return row * 128 + ((chunk ^ (row & 7)) << 4);
}

// ---------------------------------------------------------------------------
// Prep: transpose+convert Vq/Vk/Vv (fp32 [R][D]) -> bf16 [mat][d][k].
// (UNCHANGED from round 5/6 — held constant for attribution.)
// ---------------------------------------------------------------------------
__global__ __launch_bounds__(256)
void transpose_v(const float* __restrict__ V0, const float* __restrict__ V1,
                 const float* __restrict__ V2, unsigned short* __restrict__ Vt)
{
    const int mat = blockIdx.z;
    const float* src = mat == 0 ? V0 : (mat == 1 ? V1 : V2);
    const int d  = blockIdx.x * 256 + threadIdx.x;
    const int kg = blockIdx.y;                       // group of 8 k values
    short8 v;
    #pragma unroll
    for (int j = 0; j < 8; ++j)
        v[j] = (short)f2bf(src[(size_t)(kg * 8 + j) * Dc + d]);
    *(short8*)&Vt[((size_t)mat * Dc + d) * Rc + kg * 8] = v;
}

// ---------------------------------------------------------------------------
// Proj: all three x = P@V + b (+RoPE / +transpose) in one kernel.
// (UNCHANGED from round 5/6 — held constant for attribution.)
// ---------------------------------------------------------------------------
__global__ __launch_bounds__(256)
void proj_kernel(const float* __restrict__ Pq, const float* __restrict__ Pk,
                 const float* __restrict__ Pv,
                 const unsigned short* __restrict__ Vtp,  // [3][D][R] bf16
                 const float* __restrict__ bq, const float* __restrict__ bk,
                 const float* __restrict__ bv,
                 const int* __restrict__ pos_ids,
                 unsigned short* __restrict__ Qb, unsigned short* __restrict__ Kb,
                 unsigned short* __restrict__ Vta)
{
    __shared__ __align__(16) unsigned char AtB[128 * 128];  // A[m][64k] bf16 swz
    __shared__ __align__(16) unsigned char BtB[128 * 128];  // B[d][64k] bf16 swz

    const int tid = threadIdx.x;
    const int z = blockIdx.z, mat = z >> 1, b = z & 1;
    const int m0 = blockIdx.x * 128, d0 = blockIdx.y * 128;
    const int w = tid >> 6, lane = tid & 63, col = lane & 15, quad = lane >> 4;
    const int mh = w & 1, dh2 = w >> 1;

    const float* P = mat == 0 ? Pq : (mat == 1 ? Pk : Pv);
    const float* Pg = P + ((size_t)b * Mc + m0) * Rc;
    const unsigned short* Vg = Vtp + (size_t)mat * Dc * Rc + (size_t)d0 * Rc;

    const int arow = tid >> 1, ac0 = (tid & 1) * 4;
    const int brow = tid >> 1, bc0 = (tid & 1) * 4;

    float4v acc[4][4] = {};   // [mt][dt]

    for (int kc = 0; kc < 4; ++kc) {
        float4 af[8];
        uint4v br[4];
        #pragma unroll
        for (int i = 0; i < 8; ++i)
            af[i] = *(const float4*)&Pg[(size_t)arow * Rc + kc * 64 + (tid & 1) * 32 + i * 4];
        #pragma unroll
        for (int i = 0; i < 4; ++i)
            br[i] = *(const uint4v*)&Vg[(size_t)brow * Rc + kc * 64 + (bc0 + i) * 8];
        ushort8v ua[4];
        #pragma unroll
        for (int i = 0; i < 4; ++i) {
            float4 f0 = af[2 * i], f1 = af[2 * i + 1];
            ushort8v u = { f2bf(f0.x), f2bf(f0.y), f2bf(f0.z), f2bf(f0.w),
                           f2bf(f1.x), f2bf(f1.y), f2bf(f1.z), f2bf(f1.w) };
            ua[i] = u;
        }
        __syncthreads();   // previous chunk's readers done
        #pragma unroll
        for (int i = 0; i < 4; ++i) {
            *(ushort8v*)(AtB + swz(arow, ac0 + i)) = ua[i];
            *(uint4v*)(BtB + swz(brow, bc0 + i)) = br[i];
        }
        __syncthreads();

        #pragma unroll
        for (int kk = 0; kk < 2; ++kk) {
            short8 afr[4], bfr[4];
            #pragma unroll
            for (int mt = 0; mt < 4; ++mt)
                afr[mt] = *(const short8*)(AtB + swz(mh * 64 + mt * 16 + col, kk * 4 + quad));
            #pragma unroll
            for (int dt = 0; dt < 4; ++dt)
                bfr[dt] = *(const short8*)(BtB + swz(dh2 * 64 + dt * 16 + col, kk * 4 + quad));
            #pragma unroll
            for (int mt = 0; mt < 4; ++mt)
                #pragma unroll
                for (int dt = 0; dt < 4; ++dt)
                    acc[mt][dt] = __builtin_amdgcn_mfma_f32_16x16x32_bf16(
                        afr[mt], bfr[dt], acc[mt][dt], 0, 0, 0);
        }
    }

    const int head = (d0 + dh2 * 64) >> 6;
    const int bh = b * Hc + head;

    if (mat < 2) {
        const float* bias = mat == 0 ? bq : bk;
        unsigned short* outp = mat == 0 ? Qb : Kb;
        const float oscale = mat == 0 ? QSCALE : 1.0f;
        float b00 = bias[head * 64 + col],      b01 = bias[head * 64 + 16 + col];
        float b10 = bias[head * 64 + 32 + col], b11 = bias[head * 64 + 48 + col];
        float if0 = __expf(-0.28782314f * (float)col);          // 10000^(-j/32)
        float if1 = __expf(-0.28782314f * (float)(col + 16));
        #pragma unroll
        for (int mt = 0; mt < 4; ++mt)
            #pragma unroll
            for (int r = 0; r < 4; ++r) {
                int m = m0 + mh * 64 + mt * 16 + quad * 4 + r;
                float pos = (float)pos_ids[b * Mc + m];
                float a0 = pos * if0, a1 = pos * if1;
                float cs0 = __cosf(a0), sn0 = __sinf(a0);
                float cs1 = __cosf(a1), sn1 = __sinf(a1);
                float x00 = acc[mt][0][r] + b00, x10 = acc[mt][2][r] + b10;
                float x01 = acc[mt][1][r] + b01, x11 = acc[mt][3][r] + b11;
                unsigned short* og = outp + ((size_t)bh * Mc + m) * DHc;
                og[col]      = f2bf((x00 * cs0 - x10 * sn0) * oscale);
                og[32 + col] = f2bf((x00 * sn0 + x10 * cs0) * oscale);
                og[16 + col] = f2bf((x01 * cs1 - x11 * sn1) * oscale);
                og[48 + col] = f2bf((x01 * sn1 + x11 * cs1) * oscale);
            }
    } else {
        #pragma unroll
        for (int dt = 0; dt < 4; ++dt) {
            int d = d0 + dh2 * 64 + dt * 16 + col;
            float bb = bv[d];
            int dh = d & 63;
            #pragma unroll
            for (int mt = 0; mt < 4; ++mt) {
                ushort4v pv;
                #pragma unroll
                for (int r = 0; r < 4; ++r) pv[r] = f2bf(acc[mt][dt][r] + bb);
                size_t base = ((size_t)bh * DHc + dh) * Mc + m0 + mh * 64 + mt * 16 + quad * 4;
                *(ushort4v*)&Vta[base] = pv;
            }
        }
    }
}

// ---------------------------------------------------------------------------
// Attn v7: ZERO barriers in the K-loop (and in the whole kernel).
// grid (M/128=16, B*H=32) = 512 blocks, block 256 (4 waves, 32 q/wave).
// K and V fragments are loaded DIRECTLY from global (contiguous b128 in the
// Kb [bh][m][dh] / Vta [bh][dh][m] layouts); all 4 waves of a block touch the
// same 16 KB K/V tile per iter -> L1-served reuse, L2 traffic ~1 MB/CU.
// LDS is only the per-wave Ps round-trip (same-wave write->read, no barrier).
// No split-K -> each wave covers all 2048 keys and writes final output.
// ---------------------------------------------------------------------------
__global__ __launch_bounds__(256, 2)
void attn_kernel(const unsigned short* __restrict__ Qb,
                 const unsigned short* __restrict__ Kb,
                 const unsigned short* __restrict__ Vt,
                 const int* __restrict__ mask,   // [B][M]
                 float* __restrict__ out)
{
    __shared__ __align__(16) unsigned char PsAll[4][4096];   // per-wave P [32q][64k] swz

    const int tid = threadIdx.x;
    const int q0 = blockIdx.x * 128;
    const int bh = blockIdx.y;
    const int b  = bh >> 4;
    const int w = tid >> 6, lane = tid & 63, col = lane & 15, quad = lane >> 4;
    unsigned char* PsB = PsAll[w];

    // Q frags (B-operand), loop-invariant: q = q0 + w*32 + qs*16 + col
    short8 qf[2][2];
    #pragma unroll
    for (int qs = 0; qs < 2; ++qs) {
        const unsigned short* Qg =
            Qb + ((size_t)bh * Mc + q0 + w * 32 + qs * 16 + col) * DHc + quad * 8;
        qf[qs][0] = *(const short8*)Qg;
        qf[qs][1] = *(const short8*)(Qg + 32);
    }

    // lane-invariant global bases (advance by constants per kt)
    // K frag (A-op): key = kt*64 + ks*16 + col, dh = quad*8 (+32)
    const unsigned short* kp = Kb + ((size_t)bh * Mc + col) * DHc + quad * 8;
    // V frag (B-op): dh = ds*16 + col, key = kt*64 + kk*32 + quad*8
    const unsigned short* vp[4];
    #pragma unroll
    for (int ds = 0; ds < 4; ++ds)
        vp[ds] = Vt + ((size_t)bh * DHc + ds * 16 + col) * Mc + quad * 8;
    const int* mp = mask + b * Mc + quad * 4;

    float lsum[2] = {};
    float4v acc_o[2][4] = {};    // [qs][ds]

    for (int kt = 0; kt < NKT; ++kt) {
        // ---- issue all global loads up front (vmcnt-depth ILP) ----
        short8 ka0[4], ka1[4];
        #pragma unroll
        for (int ks = 0; ks < 4; ++ks) {
            const unsigned short* ra = kp + (size_t)(kt * 64 + ks * 16) * DHc;
            ka0[ks] = *(const short8*)ra;
            ka1[ks] = *(const short8*)(ra + 32);
        }
        short8 vb[4][2];
        #pragma unroll
        for (int ds = 0; ds < 4; ++ds)
            #pragma unroll
            for (int kk = 0; kk < 2; ++kk)
                vb[ds][kk] = *(const short8*)(vp[ds] + kt * 64 + kk * 32);
        int4 mv[4];
        #pragma unroll
        for (int ks = 0; ks < 4; ++ks)
            mv[ks] = *(const int4*)(mp + kt * 64 + ks * 16);

        // ---- S^T: sacc[ks][qs] = K·Q^T, D[key=ks*16+quad*4+r][q=qs*16+col] ----
        float4v sacc[4][2] = {};
        #pragma unroll
        for (int ks = 0; ks < 4; ++ks)
            #pragma unroll
            for (int qs = 0; qs < 2; ++qs) {
                sacc[ks][qs] = __builtin_amdgcn_mfma_f32_16x16x32_bf16(
                    ka0[ks], qf[qs][0], sacc[ks][qs], 0, 0, 0);
                sacc[ks][qs] = __builtin_amdgcn_mfma_f32_16x16x32_bf16(
                    ka1[ks], qf[qs][1], sacc[ks][qs], 0, 0, 0);
            }

        // ---- exp + P write to per-wave LDS (same-wave round-trip) ----
        #pragma unroll
        for (int ks = 0; ks < 4; ++ks) {
            const int* mi = (const int*)&mv[ks];
            #pragma unroll
            for (int qs = 0; qs < 2; ++qs) {
                float p0 = EXPFN(sacc[ks][qs][0] + (mi[0] ? MADD_KEEP : -1e30f));
                float p1 = EXPFN(sacc[ks][qs][1] + (mi[1] ? MADD_KEEP : -1e30f));
                float p2 = EXPFN(sacc[ks][qs][2] + (mi[2] ? MADD_KEEP : -1e30f));
                float p3 = EXPFN(sacc[ks][qs][3] + (mi[3] ? MADD_KEEP : -1e30f));
                lsum[qs] += (p0 + p1) + (p2 + p3);
                __hip_bfloat162 h01 = __float22bfloat162_rn(float2{p0, p1});
                __hip_bfloat162 h23 = __float22bfloat162_rn(float2{p2, p3});
                union { struct { __hip_bfloat162 a, b; } h; ushort4v u; } cv;
                cv.h.a = h01; cv.h.b = h23;
                int qrow = qs * 16 + col;
                *(ushort4v*)(PsB + qrow * 128 +
                             (((ks * 2 + (quad >> 1)) ^ (qrow & 7)) << 4) +
                             (quad & 1) * 8) = cv.u;
            }
        }

        // ---- PV: acc_o[qs][ds] += P (A, own Ps) * V (B, regs) ----
        #pragma unroll
        for (int kk = 0; kk < 2; ++kk) {
            short8 pa[2];
            #pragma unroll
            for (int qs = 0; qs < 2; ++qs)
                pa[qs] = *(const short8*)(PsB + swz(qs * 16 + col, kk * 4 + quad));
            #pragma unroll
            for (int ds = 0; ds < 4; ++ds)
                #pragma unroll
                for (int qs = 0; qs < 2; ++qs)
                    acc_o[qs][ds] = __builtin_amdgcn_mfma_f32_16x16x32_bf16(
                        pa[qs], vb[ds][kk], acc_o[qs][ds], 0, 0, 0);
        }
    }

    // l reduction over quads: every lane ends with full l for q = qs*16+col
    #pragma unroll
    for (int qs = 0; qs < 2; ++qs) {
        lsum[qs] += __shfl_xor(lsum[qs], 16);
        lsum[qs] += __shfl_xor(lsum[qs], 32);
    }

    // epilogue: out = O / l (0 if l==0); acc_o rows are q_local = qs*16+quad*4+r
    #pragma unroll
    for (int qs = 0; qs < 2; ++qs)
        #pragma unroll
        for (int r = 0; r < 4; ++r) {
            float lr = __shfl(lsum[qs], quad * 4 + r);
            float inv = (lr > 0.0f) ? 1.0f / lr : 0.0f;
            int m = q0 + w * 32 + qs * 16 + quad * 4 + r;
            float* og = out + ((size_t)bh * Mc + m) * DHc;
            #pragma unroll
            for (int ds = 0; ds < 4; ++ds)
                og[ds * 16 + col] = acc_o[qs][ds][r] * inv;
        }
}

extern "C" void kernel_launch(void* const* d_in, const int* in_sizes, int n_in,
                              void* d_out, int out_size, void* d_ws, size_t ws_size,
                              hipStream_t stream) {
    const float* Pq = (const float*)d_in[0];
    const float* Pk = (const float*)d_in[1];
    const float* Pv = (const float*)d_in[2];
    const float* Vq = (const float*)d_in[3];
    const float* Vk = (const float*)d_in[4];
    const float* Vv = (const float*)d_in[5];
    const float* bq = (const float*)d_in[6];
    const float* bk = (const float*)d_in[7];
    const float* bv = (const float*)d_in[8];
    const int*   am = (const int*)d_in[9];
    const int*   pid = (const int*)d_in[10];
    float* out = (float*)d_out;

    // workspace: Qb 8MB | Kb 8MB | Vta 8MB | Vtp 1.5MB
    const size_t n_el = (size_t)Bc * Hc * Mc * DHc;            // 4M elements
    unsigned short* Qb  = (unsigned short*)d_ws;
    unsigned short* Kb  = Qb + n_el;
    unsigned short* Vta = Kb + n_el;
    unsigned short* Vtp = Vta + n_el;                          // [3][D][R] bf16

    dim3 blk(256);
    transpose_v<<<dim3(Dc / 256, Rc / 8, 3), blk, 0, stream>>>(Vq, Vk, Vv, Vtp);

    proj_kernel<<<dim3(Mc / 128, Dc / 128, 6), blk, 0, stream>>>(
        Pq, Pk, Pv, Vtp, bq, bk, bv, pid, Qb, Kb, Vta);

    attn_kernel<<<dim3(Mc / 128, Bc * Hc), blk, 0, stream>>>(Qb, Kb, Vta, am, out);
}

// Round 8
// 164.173 us; speedup vs baseline: 1.4629x; 1.4629x over previous
//
#include <hip/hip_runtime.h>
#include <hip/hip_bf16.h>
#include <cstdint>
#include <cstddef>

// Problem constants (match reference)
#define Bc 2
#define Mc 2048
#define Rc 256
#define Hc 16
#define DHc 64
#define Dc (Hc * DHc)
#define NKT128 16          // 16 key tiles of 128

typedef __attribute__((ext_vector_type(8))) short short8;     // 8 bf16 (4 VGPRs)
typedef __attribute__((ext_vector_type(4))) float float4v;    // MFMA C/D frag
typedef __attribute__((ext_vector_type(4))) unsigned short ushort4v;
typedef __attribute__((ext_vector_type(8))) unsigned short ushort8v;
typedef __attribute__((ext_vector_type(4))) unsigned int uint4v;

// exp path: native exp2 (v_exp_f32); 0.125*log2(e) folded into Q at proj
#if __has_builtin(__builtin_amdgcn_exp2f)
#define EXPFN(x) __builtin_amdgcn_exp2f(x)
#define QSCALE 0.18033688f       // 0.125 * log2(e)
#define MADD_KEEP (-28.8539008f) // -20 * log2(e)
#else
#define EXPFN(x) __expf(x)
#define QSCALE 0.125f
#define MADD_KEEP (-20.0f)
#endif

// round-to-nearest-even f32 -> bf16
__device__ inline unsigned short f2bf(float f) {
    union { float f; uint32_t u; } v;
    v.f = f;
    uint32_t r = v.u + 0x7fffu + ((v.u >> 16) & 1u);
    return (unsigned short)(r >> 16);
}

// XOR-swizzled byte offset for [row][8 x 16B-chunk] LDS tiles (row = 128 B).
__device__ inline int swz(int row, int chunk) {
    return row * 128 + ((chunk ^ (row & 7)) << 4);
}

// ---------------------------------------------------------------------------
// Prep: transpose+convert Vq/Vk/Vv (fp32 [R][D]) -> bf16 [mat][d][k].
// (UNCHANGED — held constant for attribution.)
// ---------------------------------------------------------------------------
__global__ __launch_bounds__(256)
void transpose_v(const float* __restrict__ V0, const float* __restrict__ V1,
                 const float* __restrict__ V2, unsigned short* __restrict__ Vt)
{
    const int mat = blockIdx.z;
    const float* src = mat == 0 ? V0 : (mat == 1 ? V1 : V2);
    const int d  = blockIdx.x * 256 + threadIdx.x;
    const int kg = blockIdx.y;                       // group of 8 k values
    short8 v;
    #pragma unroll
    for (int j = 0; j < 8; ++j)
        v[j] = (short)f2bf(src[(size_t)(kg * 8 + j) * Dc + d]);
    *(short8*)&Vt[((size_t)mat * Dc + d) * Rc + kg * 8] = v;
}

// ---------------------------------------------------------------------------
// Proj: all three x = P@V + b (+RoPE / +transpose) in one kernel.
// grid (M/128=16, D/128=8, 6), block 256 (4 waves).
// Main loop unchanged from R5-R7. NEW epilogue: per-wave LDS transpose
// (registers -> 2B LDS writes -> b128 LDS reads -> fully-coalesced 1KB global
// stores), replacing the 64-scattered-2B-store pattern.
// ---------------------------------------------------------------------------
__global__ __launch_bounds__(256)
void proj_kernel(const float* __restrict__ Pq, const float* __restrict__ Pk,
                 const float* __restrict__ Pv,
                 const unsigned short* __restrict__ Vtp,  // [3][D][R] bf16
                 const float* __restrict__ bq, const float* __restrict__ bk,
                 const float* __restrict__ bv,
                 const int* __restrict__ pos_ids,
                 unsigned short* __restrict__ Qb, unsigned short* __restrict__ Kb,
                 unsigned short* __restrict__ Vta)
{
    __shared__ __align__(16) unsigned char SM[32768];
    unsigned char* AtB = SM;             // A[m][64k] bf16 swz (16 KB)
    unsigned char* BtB = SM + 16384;     // B[d][64k] bf16 swz (16 KB)

    const int tid = threadIdx.x;
    const int z = blockIdx.z, mat = z >> 1, b = z & 1;
    const int m0 = blockIdx.x * 128, d0 = blockIdx.y * 128;
    const int w = tid >> 6, lane = tid & 63, col = lane & 15, quad = lane >> 4;
    const int mh = w & 1, dh2 = w >> 1;

    const float* P = mat == 0 ? Pq : (mat == 1 ? Pk : Pv);
    const float* Pg = P + ((size_t)b * Mc + m0) * Rc;
    const unsigned short* Vg = Vtp + (size_t)mat * Dc * Rc + (size_t)d0 * Rc;

    const int arow = tid >> 1, ac0 = (tid & 1) * 4;
    const int brow = tid >> 1, bc0 = (tid & 1) * 4;

    float4v acc[4][4] = {};   // [mt][dt]

    for (int kc = 0; kc < 4; ++kc) {
        float4 af[8];
        uint4v br[4];
        #pragma unroll
        for (int i = 0; i < 8; ++i)
            af[i] = *(const float4*)&Pg[(size_t)arow * Rc + kc * 64 + (tid & 1) * 32 + i * 4];
        #pragma unroll
        for (int i = 0; i < 4; ++i)
            br[i] = *(const uint4v*)&Vg[(size_t)brow * Rc + kc * 64 + (bc0 + i) * 8];
        ushort8v ua[4];
        #pragma unroll
        for (int i = 0; i < 4; ++i) {
            float4 f0 = af[2 * i], f1 = af[2 * i + 1];
            ushort8v u = { f2bf(f0.x), f2bf(f0.y), f2bf(f0.z), f2bf(f0.w),
                           f2bf(f1.x), f2bf(f1.y), f2bf(f1.z), f2bf(f1.w) };
            ua[i] = u;
        }
        __syncthreads();   // previous chunk's readers done
        #pragma unroll
        for (int i = 0; i < 4; ++i) {
            *(ushort8v*)(AtB + swz(arow, ac0 + i)) = ua[i];
            *(uint4v*)(BtB + swz(brow, bc0 + i)) = br[i];
        }
        __syncthreads();

        #pragma unroll
        for (int kk = 0; kk < 2; ++kk) {
            short8 afr[4], bfr[4];
            #pragma unroll
            for (int mt = 0; mt < 4; ++mt)
                afr[mt] = *(const short8*)(AtB + swz(mh * 64 + mt * 16 + col, kk * 4 + quad));
            #pragma unroll
            for (int dt = 0; dt < 4; ++dt)
                bfr[dt] = *(const short8*)(BtB + swz(dh2 * 64 + dt * 16 + col, kk * 4 + quad));
            #pragma unroll
            for (int mt = 0; mt < 4; ++mt)
                #pragma unroll
                for (int dt = 0; dt < 4; ++dt)
                    acc[mt][dt] = __builtin_amdgcn_mfma_f32_16x16x32_bf16(
                        afr[mt], bfr[dt], acc[mt][dt], 0, 0, 0);
        }
    }

    const int head = (d0 + dh2 * 64) >> 6;
    const int bh = b * Hc + head;

    __syncthreads();   // all tile reads done -> reuse SM per wave (8 KB each)
    unsigned char* Ep = SM + w * 8192;
    const int lr0 = lane >> 3, lc = lane & 7;

    if (mat < 2) {
        // RoPE in registers, then LDS transpose [m64][dh64] -> coalesced stores
        const float* bias = mat == 0 ? bq : bk;
        unsigned short* outp = mat == 0 ? Qb : Kb;
        const float oscale = mat == 0 ? QSCALE : 1.0f;
        float b00 = bias[head * 64 + col],      b01 = bias[head * 64 + 16 + col];
        float b10 = bias[head * 64 + 32 + col], b11 = bias[head * 64 + 48 + col];
        float if0 = __expf(-0.28782314f * (float)col);          // 10000^(-j/32)
        float if1 = __expf(-0.28782314f * (float)(col + 16));
        unsigned short* Epw = (unsigned short*)Ep;              // [m 64][dh 64]
        #pragma unroll
        for (int mt = 0; mt < 4; ++mt)
            #pragma unroll
            for (int r = 0; r < 4; ++r) {
                int ml = mt * 16 + quad * 4 + r;                // local m
                int m = m0 + mh * 64 + ml;
                float pos = (float)pos_ids[b * Mc + m];
                float a0 = pos * if0, a1 = pos * if1;
                float cs0 = __cosf(a0), sn0 = __sinf(a0);
                float cs1 = __cosf(a1), sn1 = __sinf(a1);
                float x00 = acc[mt][0][r] + b00, x10 = acc[mt][2][r] + b10;
                float x01 = acc[mt][1][r] + b01, x11 = acc[mt][3][r] + b11;
                Epw[ml * 64 + col]      = f2bf((x00 * cs0 - x10 * sn0) * oscale);
                Epw[ml * 64 + 32 + col] = f2bf((x00 * sn0 + x10 * cs0) * oscale);
                Epw[ml * 64 + 16 + col] = f2bf((x01 * cs1 - x11 * sn1) * oscale);
                Epw[ml * 64 + 48 + col] = f2bf((x01 * sn1 + x11 * cs1) * oscale);
            }
        // same-wave readback (8 b128) + 1KB-coalesced global stores
        unsigned short* ogb = outp + ((size_t)bh * Mc + m0 + mh * 64) * DHc;
        #pragma unroll
        for (int i = 0; i < 8; ++i) {
            int lr = lr0 + i * 8;
            uint4v t = *(const uint4v*)&Epw[lr * 64 + lc * 8];
            *(uint4v*)&ogb[(size_t)lr * DHc + lc * 8] = t;
        }
    } else {
        // V: LDS transpose [dh 64][m 64] (XOR-chunked) -> coalesced [dh][m] rows
        #pragma unroll
        for (int dt = 0; dt < 4; ++dt) {
            int dhl = dt * 16 + col;
            float bb = bv[d0 + dh2 * 64 + dhl];
            #pragma unroll
            for (int mt = 0; mt < 4; ++mt) {
                ushort4v pv;
                #pragma unroll
                for (int r = 0; r < 4; ++r) pv[r] = f2bf(acc[mt][dt][r] + bb);
                int chunk = (mt * 2 + (quad >> 1)) ^ (dhl & 7);
                *(ushort4v*)(Ep + dhl * 128 + (chunk << 4) + (quad & 1) * 8) = pv;
            }
        }
        unsigned short* ogb = Vta + (size_t)bh * DHc * Mc + m0 + mh * 64;
        #pragma unroll
        for (int i = 0; i < 8; ++i) {
            int lr = lr0 + i * 8;     // local dh row
            uint4v t = *(const uint4v*)(Ep + lr * 128 + ((lc ^ (lr & 7)) << 4));
            *(uint4v*)&ogb[(size_t)lr * Mc + lc * 8] = t;
        }
    }
}

// ---------------------------------------------------------------------------
// Attn v8: R3/R4-proven 2-barrier LDS-staged structure, BK=128.
// grid (M/128=16, B*H=32) = 512 blocks, block 256 (4 waves, 32 q/wave).
// Per iter: stage 16KB K + 16KB V (coalesced b128), 16 barrier-pairs total
// (half of R3's 32). Per-wave Ps [32q][128k] (8KB), same-wave round-trip,
// no third barrier. LDS = 64 KB -> 2 blocks/CU (same co-residency as R3).
// ---------------------------------------------------------------------------
__global__ __launch_bounds__(256, 2)
void attn_kernel(const unsigned short* __restrict__ Qb,
                 const unsigned short* __restrict__ Kb,
                 const unsigned short* __restrict__ Vt,
                 const int* __restrict__ mask,   // [B][M]
                 float* __restrict__ out)
{
    __shared__ __align__(16) unsigned char KsB[16384];      // [key128][dh64] swz&7
    __shared__ __align__(16) unsigned char VsB[16384];      // [dh64][key128] 256B rows swz&15
    __shared__ __align__(16) unsigned char PsAll[4][8192];  // per-wave [q32][key128]

    const int tid = threadIdx.x;
    const int q0 = blockIdx.x * 128;
    const int bh = blockIdx.y;
    const int b  = bh >> 4;
    const int w = tid >> 6, lane = tid & 63, col = lane & 15, quad = lane >> 4;
    unsigned char* PsB = PsAll[w];

    // Q frags (B-operand), loop-invariant: q = q0 + w*32 + qs*16 + col
    short8 qf[2][2];
    #pragma unroll
    for (int qs = 0; qs < 2; ++qs) {
        const unsigned short* Qg =
            Qb + ((size_t)bh * Mc + q0 + w * 32 + qs * 16 + col) * DHc + quad * 8;
        qf[qs][0] = *(const short8*)Qg;
        qf[qs][1] = *(const short8*)(Qg + 32);
    }

    // staging: K 128 rows x 128B (thread: row tid>>1, 64B); V 64 rows x 256B
    const int krow = tid >> 1, kc0 = (tid & 1) * 4;
    const int vrow = tid >> 2, vc0 = (tid & 3) * 4;
    int kdst[4], vdst[4];
    #pragma unroll
    for (int i = 0; i < 4; ++i) {
        kdst[i] = krow * 128 + (((kc0 + i) ^ (krow & 7)) << 4);
        vdst[i] = vrow * 256 + (((vc0 + i) ^ (vrow & 15)) << 4);
    }

    const unsigned short* Kg = Kb + (size_t)bh * Mc * DHc;
    const unsigned short* Vg = Vt + (size_t)bh * DHc * Mc;
    const int* mp = mask + b * Mc + quad * 4;

    uint4v kr[4], vr[4];
    #pragma unroll
    for (int i = 0; i < 4; ++i) {
        kr[i] = *(const uint4v*)&Kg[(size_t)krow * DHc + (kc0 + i) * 8];
        vr[i] = *(const uint4v*)&Vg[(size_t)vrow * Mc + (vc0 + i) * 8];
    }

    float lsum[2] = {};
    float4v acc_o[2][4] = {};    // [qs][ds]

    for (int kt = 0; kt < NKT128; ++kt) {
        __syncthreads();   // b1: prior iter's tile reads complete
        #pragma unroll
        for (int i = 0; i < 4; ++i) *(uint4v*)(KsB + kdst[i]) = kr[i];
        #pragma unroll
        for (int i = 0; i < 4; ++i) *(uint4v*)(VsB + vdst[i]) = vr[i];
        __syncthreads();   // b2: tiles visible

        if (kt + 1 < NKT128) {   // prefetch next tile (covered by compute phase)
            const unsigned short* Kn = Kg + (size_t)(kt + 1) * 128 * DHc;
            #pragma unroll
            for (int i = 0; i < 4; ++i) {
                kr[i] = *(const uint4v*)&Kn[(size_t)krow * DHc + (kc0 + i) * 8];
                vr[i] = *(const uint4v*)&Vg[(size_t)vrow * Mc + (kt + 1) * 128 + (vc0 + i) * 8];
            }
        }

        // ---- S^T + exp + Ps, 8 groups of 16 keys ----
        #pragma unroll
        for (int ks = 0; ks < 8; ++ks) {
            int row = ks * 16 + col;
            short8 a0 = *(const short8*)(KsB + row * 128 + ((quad ^ (row & 7)) << 4));
            short8 a1 = *(const short8*)(KsB + row * 128 + (((4 + quad) ^ (row & 7)) << 4));
            int4 mv = *(const int4*)(mp + kt * 128 + ks * 16);
            const int* mi = (const int*)&mv;
            #pragma unroll
            for (int qs = 0; qs < 2; ++qs) {
                float4v sacc = {};
                sacc = __builtin_amdgcn_mfma_f32_16x16x32_bf16(a0, qf[qs][0], sacc, 0, 0, 0);
                sacc = __builtin_amdgcn_mfma_f32_16x16x32_bf16(a1, qf[qs][1], sacc, 0, 0, 0);
                float p0 = EXPFN(sacc[0] + (mi[0] ? MADD_KEEP : -1e30f));
                float p1 = EXPFN(sacc[1] + (mi[1] ? MADD_KEEP : -1e30f));
                float p2 = EXPFN(sacc[2] + (mi[2] ? MADD_KEEP : -1e30f));
                float p3 = EXPFN(sacc[3] + (mi[3] ? MADD_KEEP : -1e30f));
                lsum[qs] += (p0 + p1) + (p2 + p3);
                __hip_bfloat162 h01 = __float22bfloat162_rn(float2{p0, p1});
                __hip_bfloat162 h23 = __float22bfloat162_rn(float2{p2, p3});
                union { struct { __hip_bfloat162 a, bb; } h; ushort4v u; } cv;
                cv.h.a = h01; cv.h.bb = h23;
                int qrow = qs * 16 + col;
                *(ushort4v*)(PsB + qrow * 256 +
                             (((ks * 2 + (quad >> 1)) ^ (qrow & 15)) << 4) +
                             (quad & 1) * 8) = cv.u;
            }
        }

        // ---- PV: 4 k-chunks of 32 keys ----
        #pragma unroll
        for (int kk = 0; kk < 4; ++kk) {
            short8 pa[2];
            #pragma unroll
            for (int qs = 0; qs < 2; ++qs) {
                int qrow = qs * 16 + col;
                pa[qs] = *(const short8*)(PsB + qrow * 256 +
                                          (((kk * 4 + quad) ^ (qrow & 15)) << 4));
            }
            #pragma unroll
            for (int ds = 0; ds < 4; ++ds) {
                int vrw = ds * 16 + col;
                short8 vb = *(const short8*)(VsB + vrw * 256 +
                                             (((kk * 4 + quad) ^ (vrw & 15)) << 4));
                #pragma unroll
                for (int qs = 0; qs < 2; ++qs)
                    acc_o[qs][ds] = __builtin_amdgcn_mfma_f32_16x16x32_bf16(
                        pa[qs], vb, acc_o[qs][ds], 0, 0, 0);
            }
        }
    }

    // l reduction over quads: every lane ends with full l for q = qs*16+col
    #pragma unroll
    for (int qs = 0; qs < 2; ++qs) {
        lsum[qs] += __shfl_xor(lsum[qs], 16);
        lsum[qs] += __shfl_xor(lsum[qs], 32);
    }

    // epilogue: out = O / l (0 if l==0)
    #pragma unroll
    for (int qs = 0; qs < 2; ++qs)
        #pragma unroll
        for (int r = 0; r < 4; ++r) {
            float lr = __shfl(lsum[qs], quad * 4 + r);
            float inv = (lr > 0.0f) ? 1.0f / lr : 0.0f;
            int m = q0 + w * 32 + qs * 16 + quad * 4 + r;
            float* og = out + ((size_t)bh * Mc + m) * DHc;
            #pragma unroll
            for (int ds = 0; ds < 4; ++ds)
                og[ds * 16 + col] = acc_o[qs][ds][r] * inv;
        }
}

extern "C" void kernel_launch(void* const* d_in, const int* in_sizes, int n_in,
                              void* d_out, int out_size, void* d_ws, size_t ws_size,
                              hipStream_t stream) {
    const float* Pq = (const float*)d_in[0];
    const float* Pk = (const float*)d_in[1];
    const float* Pv = (const float*)d_in[2];
    const float* Vq = (const float*)d_in[3];
    const float* Vk = (const float*)d_in[4];
    const float* Vv = (const float*)d_in[5];
    const float* bq = (const float*)d_in[6];
    const float* bk = (const float*)d_in[7];
    const float* bv = (const float*)d_in[8];
    const int*   am = (const int*)d_in[9];
    const int*   pid = (const int*)d_in[10];
    float* out = (float*)d_out;

    // workspace: Qb 8MB | Kb 8MB | Vta 8MB | Vtp 1.5MB
    const size_t n_el = (size_t)Bc * Hc * Mc * DHc;            // 4M elements
    unsigned short* Qb  = (unsigned short*)d_ws;
    unsigned short* Kb  = Qb + n_el;
    unsigned short* Vta = Kb + n_el;
    unsigned short* Vtp = Vta + n_el;                          // [3][D][R] bf16

    dim3 blk(256);
    transpose_v<<<dim3(Dc / 256, Rc / 8, 3), blk, 0, stream>>>(Vq, Vk, Vv, Vtp);

    proj_kernel<<<dim3(Mc / 128, Dc / 128, 6), blk, 0, stream>>>(
        Pq, Pk, Pv, Vtp, bq, bk, bv, pid, Qb, Kb, Vta);

    attn_kernel<<<dim3(Mc / 128, Bc * Hc), blk, 0, stream>>>(Qb, Kb, Vta, am, out);
}

// Round 10
// 159.288 us; speedup vs baseline: 1.5077x; 1.0307x over previous
//
#include <hip/hip_runtime.h>
#include <hip/hip_bf16.h>
#include <cstdint>
#include <cstddef>

// Problem constants (match reference)
#define Bc 2
#define Mc 2048
#define Rc 256
#define Hc 16
#define DHc 64
#define Dc (Hc * DHc)
#define NKT128 16          // 16 key tiles of 128

typedef __attribute__((ext_vector_type(8))) short short8;     // 8 bf16 (4 VGPRs)
typedef __attribute__((ext_vector_type(4))) float float4v;    // MFMA C/D frag
typedef __attribute__((ext_vector_type(4))) unsigned short ushort4v;
typedef __attribute__((ext_vector_type(8))) unsigned short ushort8v;
typedef __attribute__((ext_vector_type(4))) unsigned int uint4v;

// exp path: native exp2 (v_exp_f32); 0.125*log2(e) folded into Q at proj
#if __has_builtin(__builtin_amdgcn_exp2f)
#define EXPFN(x) __builtin_amdgcn_exp2f(x)
#define QSCALE 0.18033688f       // 0.125 * log2(e)
#define MADD_KEEP (-28.8539008f) // -20 * log2(e)
#else
#define EXPFN(x) __expf(x)
#define QSCALE 0.125f
#define MADD_KEEP (-20.0f)
#endif

// round-to-nearest-even f32 -> bf16
__device__ inline unsigned short f2bf(float f) {
    union { float f; uint32_t u; } v;
    v.f = f;
    uint32_t r = v.u + 0x7fffu + ((v.u >> 16) & 1u);
    return (unsigned short)(r >> 16);
}

// XOR-swizzled byte offset for [row][8 x 16B-chunk] LDS tiles (row = 128 B).
__device__ inline int swz(int row, int chunk) {
    return row * 128 + ((chunk ^ (row & 7)) << 4);
}

// ---------------------------------------------------------------------------
// Prep 1: transpose+convert Vq/Vk/Vv (fp32 [R][D]) -> bf16 [mat][d][k].
// (R8 byte-identical — proven.)
// ---------------------------------------------------------------------------
__global__ __launch_bounds__(256)
void transpose_v(const float* __restrict__ V0, const float* __restrict__ V1,
                 const float* __restrict__ V2, unsigned short* __restrict__ Vt)
{
    const int mat = blockIdx.z;
    const float* src = mat == 0 ? V0 : (mat == 1 ? V1 : V2);
    const int d  = blockIdx.x * 256 + threadIdx.x;
    const int kg = blockIdx.y;                       // group of 8 k values
    short8 v;
    #pragma unroll
    for (int j = 0; j < 8; ++j)
        v[j] = (short)f2bf(src[(size_t)(kg * 8 + j) * Dc + d]);
    *(short8*)&Vt[((size_t)mat * Dc + d) * Rc + kg * 8] = v;
}

// ---------------------------------------------------------------------------
// Prep 2: P fp32 -> bf16 (separate kernel, R3-proven structure; packed cvt).
// grid (512, 3), block 256; 8 floats/thread.
// ---------------------------------------------------------------------------
__global__ __launch_bounds__(256)
void convP(const float* __restrict__ P0, const float* __restrict__ P1,
           const float* __restrict__ P2, unsigned short* __restrict__ Pb)
{
    const int mat = blockIdx.y;
    const float* src = mat == 0 ? P0 : (mat == 1 ? P1 : P2);
    size_t idx = ((size_t)blockIdx.x * 256 + threadIdx.x) * 8;
    float4 f0 = *(const float4*)&src[idx];
    float4 f1 = *(const float4*)&src[idx + 4];
    union { struct { __hip_bfloat162 a, b, c, d; } h; ushort8v u; } cv;
    cv.h.a = __float22bfloat162_rn(float2{f0.x, f0.y});
    cv.h.b = __float22bfloat162_rn(float2{f0.z, f0.w});
    cv.h.c = __float22bfloat162_rn(float2{f1.x, f1.y});
    cv.h.d = __float22bfloat162_rn(float2{f1.z, f1.w});
    *(ushort8v*)&Pb[(size_t)mat * Bc * Mc * Rc + idx] = cv.u;
}

// ---------------------------------------------------------------------------
// Proj: all three x = P@V + b (+RoPE / +transpose) in one kernel.
// grid (M/128=16, D/128=8, 6), block 256 (4 waves).
// R8 internals; ONLY change: A-staging from pre-converted bf16 Pb
// (4 b128 copies/thread/chunk — same shape as the proven B-staging path).
// ---------------------------------------------------------------------------
__global__ __launch_bounds__(256)
void proj_kernel(const unsigned short* __restrict__ Pb,   // [3][B][M][R] bf16
                 const unsigned short* __restrict__ Vtp,  // [3][D][R] bf16
                 const float* __restrict__ bq, const float* __restrict__ bk,
                 const float* __restrict__ bv,
                 const int* __restrict__ pos_ids,
                 unsigned short* __restrict__ Qb, unsigned short* __restrict__ Kb,
                 unsigned short* __restrict__ Vta)
{
    __shared__ __align__(16) unsigned char SM[32768];
    unsigned char* AtB = SM;             // A[m][64k] bf16 swz (16 KB)
    unsigned char* BtB = SM + 16384;     // B[d][64k] bf16 swz (16 KB)

    const int tid = threadIdx.x;
    const int z = blockIdx.z, mat = z >> 1, b = z & 1;
    const int m0 = blockIdx.x * 128, d0 = blockIdx.y * 128;
    const int w = tid >> 6, lane = tid & 63, col = lane & 15, quad = lane >> 4;
    const int mh = w & 1, dh2 = w >> 1;

    const unsigned short* Ag = Pb + ((size_t)mat * Bc + b) * Mc * Rc + (size_t)m0 * Rc;
    const unsigned short* Vg = Vtp + (size_t)mat * Dc * Rc + (size_t)d0 * Rc;

    const int arow = tid >> 1, ac0 = (tid & 1) * 4;
    const int brow = tid >> 1, bc0 = (tid & 1) * 4;

    float4v acc[4][4] = {};   // [mt][dt]

    for (int kc = 0; kc < 4; ++kc) {
        uint4v ar[4], br[4];
        #pragma unroll
        for (int i = 0; i < 4; ++i) {
            ar[i] = *(const uint4v*)&Ag[(size_t)arow * Rc + kc * 64 + (ac0 + i) * 8];
            br[i] = *(const uint4v*)&Vg[(size_t)brow * Rc + kc * 64 + (bc0 + i) * 8];
        }
        __syncthreads();   // previous chunk's readers done
        #pragma unroll
        for (int i = 0; i < 4; ++i) {
            *(uint4v*)(AtB + swz(arow, ac0 + i)) = ar[i];
            *(uint4v*)(BtB + swz(brow, bc0 + i)) = br[i];
        }
        __syncthreads();

        #pragma unroll
        for (int kk = 0; kk < 2; ++kk) {
            short8 afr[4], bfr[4];
            #pragma unroll
            for (int mt = 0; mt < 4; ++mt)
                afr[mt] = *(const short8*)(AtB + swz(mh * 64 + mt * 16 + col, kk * 4 + quad));
            #pragma unroll
            for (int dt = 0; dt < 4; ++dt)
                bfr[dt] = *(const short8*)(BtB + swz(dh2 * 64 + dt * 16 + col, kk * 4 + quad));
            #pragma unroll
            for (int mt = 0; mt < 4; ++mt)
                #pragma unroll
                for (int dt = 0; dt < 4; ++dt)
                    acc[mt][dt] = __builtin_amdgcn_mfma_f32_16x16x32_bf16(
                        afr[mt], bfr[dt], acc[mt][dt], 0, 0, 0);
        }
    }

    const int head = (d0 + dh2 * 64) >> 6;
    const int bh = b * Hc + head;

    __syncthreads();   // all tile reads done -> reuse SM per wave (8 KB each)
    unsigned char* Ep = SM + w * 8192;
    const int lr0 = lane >> 3, lc = lane & 7;

    if (mat < 2) {
        // RoPE in registers, then LDS transpose [m64][dh64] -> coalesced stores
        const float* bias = mat == 0 ? bq : bk;
        unsigned short* outp = mat == 0 ? Qb : Kb;
        const float oscale = mat == 0 ? QSCALE : 1.0f;
        float b00 = bias[head * 64 + col],      b01 = bias[head * 64 + 16 + col];
        float b10 = bias[head * 64 + 32 + col], b11 = bias[head * 64 + 48 + col];
        float if0 = __expf(-0.28782314f * (float)col);          // 10000^(-j/32)
        float if1 = __expf(-0.28782314f * (float)(col + 16));
        unsigned short* Epw = (unsigned short*)Ep;              // [m 64][dh 64]
        #pragma unroll
        for (int mt = 0; mt < 4; ++mt)
            #pragma unroll
            for (int r = 0; r < 4; ++r) {
                int ml = mt * 16 + quad * 4 + r;                // local m
                int m = m0 + mh * 64 + ml;
                float pos = (float)pos_ids[b * Mc + m];
                float a0 = pos * if0, a1 = pos * if1;
                float cs0 = __cosf(a0), sn0 = __sinf(a0);
                float cs1 = __cosf(a1), sn1 = __sinf(a1);
                float x00 = acc[mt][0][r] + b00, x10 = acc[mt][2][r] + b10;
                float x01 = acc[mt][1][r] + b01, x11 = acc[mt][3][r] + b11;
                Epw[ml * 64 + col]      = f2bf((x00 * cs0 - x10 * sn0) * oscale);
                Epw[ml * 64 + 32 + col] = f2bf((x00 * sn0 + x10 * cs0) * oscale);
                Epw[ml * 64 + 16 + col] = f2bf((x01 * cs1 - x11 * sn1) * oscale);
                Epw[ml * 64 + 48 + col] = f2bf((x01 * sn1 + x11 * cs1) * oscale);
            }
        // same-wave readback (8 b128) + 1KB-coalesced global stores
        unsigned short* ogb = outp + ((size_t)bh * Mc + m0 + mh * 64) * DHc;
        #pragma unroll
        for (int i = 0; i < 8; ++i) {
            int lr = lr0 + i * 8;
            uint4v t = *(const uint4v*)&Epw[lr * 64 + lc * 8];
            *(uint4v*)&ogb[(size_t)lr * DHc + lc * 8] = t;
        }
    } else {
        // V: LDS transpose [dh 64][m 64] (XOR-chunked) -> coalesced [dh][m] rows
        #pragma unroll
        for (int dt = 0; dt < 4; ++dt) {
            int dhl = dt * 16 + col;
            float bb = bv[d0 + dh2 * 64 + dhl];
            #pragma unroll
            for (int mt = 0; mt < 4; ++mt) {
                ushort4v pv;
                #pragma unroll
                for (int r = 0; r < 4; ++r) pv[r] = f2bf(acc[mt][dt][r] + bb);
                int chunk = (mt * 2 + (quad >> 1)) ^ (dhl & 7);
                *(ushort4v*)(Ep + dhl * 128 + (chunk << 4) + (quad & 1) * 8) = pv;
            }
        }
        unsigned short* ogb = Vta + (size_t)bh * DHc * Mc + m0 + mh * 64;
        #pragma unroll
        for (int i = 0; i < 8; ++i) {
            int lr = lr0 + i * 8;     // local dh row
            uint4v t = *(const uint4v*)(Ep + lr * 128 + ((lc ^ (lr & 7)) << 4));
            *(uint4v*)&ogb[(size_t)lr * Mc + lc * 8] = t;
        }
    }
}

// ---------------------------------------------------------------------------
// Attn v8 (R8 byte-identical — best known, 65.6 µs).
// grid (M/128=16, B*H=32) = 512 blocks, block 256 (4 waves, 32 q/wave).
// ---------------------------------------------------------------------------
__global__ __launch_bounds__(256, 2)
void attn_kernel(const unsigned short* __restrict__ Qb,
                 const unsigned short* __restrict__ Kb,
                 const unsigned short* __restrict__ Vt,
                 const int* __restrict__ mask,   // [B][M]
                 float* __restrict__ out)
{
    __shared__ __align__(16) unsigned char KsB[16384];      // [key128][dh64] swz&7
    __shared__ __align__(16) unsigned char VsB[16384];      // [dh64][key128] 256B rows swz&15
    __shared__ __align__(16) unsigned char PsAll[4][8192];  // per-wave [q32][key128]

    const int tid = threadIdx.x;
    const int q0 = blockIdx.x * 128;
    const int bh = blockIdx.y;
    const int b  = bh >> 4;
    const int w = tid >> 6, lane = tid & 63, col = lane & 15, quad = lane >> 4;
    unsigned char* PsB = PsAll[w];

    // Q frags (B-operand), loop-invariant: q = q0 + w*32 + qs*16 + col
    short8 qf[2][2];
    #pragma unroll
    for (int qs = 0; qs < 2; ++qs) {
        const unsigned short* Qg =
            Qb + ((size_t)bh * Mc + q0 + w * 32 + qs * 16 + col) * DHc + quad * 8;
        qf[qs][0] = *(const short8*)Qg;
        qf[qs][1] = *(const short8*)(Qg + 32);
    }

    // staging: K 128 rows x 128B (thread: row tid>>1, 64B); V 64 rows x 256B
    const int krow = tid >> 1, kc0 = (tid & 1) * 4;
    const int vrow = tid >> 2, vc0 = (tid & 3) * 4;
    int kdst[4], vdst[4];
    #pragma unroll
    for (int i = 0; i < 4; ++i) {
        kdst[i] = krow * 128 + (((kc0 + i) ^ (krow & 7)) << 4);
        vdst[i] = vrow * 256 + (((vc0 + i) ^ (vrow & 15)) << 4);
    }

    const unsigned short* Kg = Kb + (size_t)bh * Mc * DHc;
    const unsigned short* Vg = Vt + (size_t)bh * DHc * Mc;
    const int* mp = mask + b * Mc + quad * 4;

    uint4v kr[4], vr[4];
    #pragma unroll
    for (int i = 0; i < 4; ++i) {
        kr[i] = *(const uint4v*)&Kg[(size_t)krow * DHc + (kc0 + i) * 8];
        vr[i] = *(const uint4v*)&Vg[(size_t)vrow * Mc + (vc0 + i) * 8];
    }

    float lsum[2] = {};
    float4v acc_o[2][4] = {};    // [qs][ds]

    for (int kt = 0; kt < NKT128; ++kt) {
        __syncthreads();   // b1: prior iter's tile reads complete
        #pragma unroll
        for (int i = 0; i < 4; ++i) *(uint4v*)(KsB + kdst[i]) = kr[i];
        #pragma unroll
        for (int i = 0; i < 4; ++i) *(uint4v*)(VsB + vdst[i]) = vr[i];
        __syncthreads();   // b2: tiles visible

        if (kt + 1 < NKT128) {   // prefetch next tile (covered by compute phase)
            const unsigned short* Kn = Kg + (size_t)(kt + 1) * 128 * DHc;
            #pragma unroll
            for (int i = 0; i < 4; ++i) {
                kr[i] = *(const uint4v*)&Kn[(size_t)krow * DHc + (kc0 + i) * 8];
                vr[i] = *(const uint4v*)&Vg[(size_t)vrow * Mc + (kt + 1) * 128 + (vc0 + i) * 8];
            }
        }

        // ---- S^T + exp + Ps, 8 groups of 16 keys ----
        #pragma unroll
        for (int ks = 0; ks < 8; ++ks) {
            int row = ks * 16 + col;
            short8 a0 = *(const short8*)(KsB + row * 128 + ((quad ^ (row & 7)) << 4));
            short8 a1 = *(const short8*)(KsB + row * 128 + (((4 + quad) ^ (row & 7)) << 4));
            int4 mv = *(const int4*)(mp + kt * 128 + ks * 16);
            const int* mi = (const int*)&mv;
            #pragma unroll
            for (int qs = 0; qs < 2; ++qs) {
                float4v sacc = {};
                sacc = __builtin_amdgcn_mfma_f32_16x16x32_bf16(a0, qf[qs][0], sacc, 0, 0, 0);
                sacc = __builtin_amdgcn_mfma_f32_16x16x32_bf16(a1, qf[qs][1], sacc, 0, 0, 0);
                float p0 = EXPFN(sacc[0] + (mi[0] ? MADD_KEEP : -1e30f));
                float p1 = EXPFN(sacc[1] + (mi[1] ? MADD_KEEP : -1e30f));
                float p2 = EXPFN(sacc[2] + (mi[2] ? MADD_KEEP : -1e30f));
                float p3 = EXPFN(sacc[3] + (mi[3] ? MADD_KEEP : -1e30f));
                lsum[qs] += (p0 + p1) + (p2 + p3);
                __hip_bfloat162 h01 = __float22bfloat162_rn(float2{p0, p1});
                __hip_bfloat162 h23 = __float22bfloat162_rn(float2{p2, p3});
                union { struct { __hip_bfloat162 a, bb; } h; ushort4v u; } cv;
                cv.h.a = h01; cv.h.bb = h23;
                int qrow = qs * 16 + col;
                *(ushort4v*)(PsB + qrow * 256 +
                             (((ks * 2 + (quad >> 1)) ^ (qrow & 15)) << 4) +
                             (quad & 1) * 8) = cv.u;
            }
        }

        // ---- PV: 4 k-chunks of 32 keys ----
        #pragma unroll
        for (int kk = 0; kk < 4; ++kk) {
            short8 pa[2];
            #pragma unroll
            for (int qs = 0; qs < 2; ++qs) {
                int qrow = qs * 16 + col;
                pa[qs] = *(const short8*)(PsB + qrow * 256 +
                                          (((kk * 4 + quad) ^ (qrow & 15)) << 4));
            }
            #pragma unroll
            for (int ds = 0; ds < 4; ++ds) {
                int vrw = ds * 16 + col;
                short8 vb = *(const short8*)(VsB + vrw * 256 +
                                             (((kk * 4 + quad) ^ (vrw & 15)) << 4));
                #pragma unroll
                for (int qs = 0; qs < 2; ++qs)
                    acc_o[qs][ds] = __builtin_amdgcn_mfma_f32_16x16x32_bf16(
                        pa[qs], vb, acc_o[qs][ds], 0, 0, 0);
            }
        }
    }

    // l reduction over quads: every lane ends with full l for q = qs*16+col
    #pragma unroll
    for (int qs = 0; qs < 2; ++qs) {
        lsum[qs] += __shfl_xor(lsum[qs], 16);
        lsum[qs] += __shfl_xor(lsum[qs], 32);
    }

    // epilogue: out = O / l (0 if l==0)
    #pragma unroll
    for (int qs = 0; qs < 2; ++qs)
        #pragma unroll
        for (int r = 0; r < 4; ++r) {
            float lr = __shfl(lsum[qs], quad * 4 + r);
            float inv = (lr > 0.0f) ? 1.0f / lr : 0.0f;
            int m = q0 + w * 32 + qs * 16 + quad * 4 + r;
            float* og = out + ((size_t)bh * Mc + m) * DHc;
            #pragma unroll
            for (int ds = 0; ds < 4; ++ds)
                og[ds * 16 + col] = acc_o[qs][ds][r] * inv;
        }
}

extern "C" void kernel_launch(void* const* d_in, const int* in_sizes, int n_in,
                              void* d_out, int out_size, void* d_ws, size_t ws_size,
                              hipStream_t stream) {
    const float* Pq = (const float*)d_in[0];
    const float* Pk = (const float*)d_in[1];
    const float* Pv = (const float*)d_in[2];
    const float* Vq = (const float*)d_in[3];
    const float* Vk = (const float*)d_in[4];
    const float* Vv = (const float*)d_in[5];
    const float* bq = (const float*)d_in[6];
    const float* bk = (const float*)d_in[7];
    const float* bv = (const float*)d_in[8];
    const int*   am = (const int*)d_in[9];
    const int*   pid = (const int*)d_in[10];
    float* out = (float*)d_out;

    // workspace: Qb 8MB | Kb 8MB | Vta 8MB | Vtp 1.5MB | Pb 6MB
    const size_t n_el = (size_t)Bc * Hc * Mc * DHc;            // 4M elements
    unsigned short* Qb  = (unsigned short*)d_ws;
    unsigned short* Kb  = Qb + n_el;
    unsigned short* Vta = Kb + n_el;
    unsigned short* Vtp = Vta + n_el;                          // [3][D][R] bf16
    unsigned short* Pb  = Vtp + (size_t)3 * Dc * Rc;           // [3][B][M][R] bf16

    dim3 blk(256);
    transpose_v<<<dim3(Dc / 256, Rc / 8, 3), blk, 0, stream>>>(Vq, Vk, Vv, Vtp);
    convP<<<dim3(512, 3), blk, 0, stream>>>(Pq, Pk, Pv, Pb);

    proj_kernel<<<dim3(Mc / 128, Dc / 128, 6), blk, 0, stream>>>(
        Pb, Vtp, bq, bk, bv, pid, Qb, Kb, Vta);

    attn_kernel<<<dim3(Mc / 128, Bc * Hc), blk, 0, stream>>>(Qb, Kb, Vta, am, out);
}